// Round 1
// 680.888 us; speedup vs baseline: 1.0086x; 1.0086x over previous
//
#include <hip/hip_runtime.h>
#include <hip/hip_bf16.h>
#include <math.h>

// Problem constants (B=8, S=4096, H=1024, E=64, Hh=512)
#define N_TOK 32768
#define HDIM 1024
#define HH 512
#define NOUT 576   // 512 h-cols + 64 router cols
#define BM 128
#define BN 64
#define BK 32
#define THREADS 256
// OpenBLAS sgemm k-panel size (Haswell/Zen SGEMM_DEFAULT_Q)
#define KC 384

// Output layout in d_out (all float32):
#define OFF_SELW 0
#define OFF_SELI 262144
#define OFF_CONF 524288
#define OFF_LOG  557056

// Static device scratch
__device__ float  g_Bmat[HDIM * NOUT];      // fused [k][j] fp32 (W1^T | Wr^T)
__device__ double g_partial[N_TOK * 8];     // per-token per-h-tile fp64 partials

// ---------------- kernel 0: build fused B matrix ----------------
__global__ __launch_bounds__(256) void k_build(const float* __restrict__ W1,
                                               const float* __restrict__ Wr) {
  int idx = blockIdx.x * 256 + threadIdx.x;   // < HDIM*NOUT = 589824 exactly
  int k = idx / NOUT;
  int j = idx - k * NOUT;
  float v = (j < HH) ? W1[(size_t)j * HDIM + k] : Wr[(size_t)(j - HH) * HDIM + k];
  g_Bmat[idx] = v;
}

// ---------------- kernel 1: fused GEMM, OpenBLAS-faithful fp32 ----------------
// Per output element: fp32 fmaf chain, k ascending, blocked in panels of KC=384:
//   res = ((P0 + P1) + P2), Pi = sequential fmaf chain from 0 over its k-range.
// This reproduces OpenBLAS sgemm's per-element reduction order bit-exactly.
__global__ __launch_bounds__(THREADS) void k_gemm(const float* __restrict__ A,
                                                  const float* __restrict__ b1,
                                                  const float* __restrict__ W2,
                                                  const float* __restrict__ b_router,
                                                  float* __restrict__ out_logits) {
  __shared__ float As[BK][BM];   // 16 KB, transposed: As[k][m]
  __shared__ float Bs[BK][BN];   // 8 KB

  // XCD swizzle: 9 n-tiles of one token-tile share blockIdx%8 -> same XCD L2
  int bid = blockIdx.x;          // 0..2303
  int xcd = bid & 7;
  int s   = bid >> 3;            // 0..287
  int j   = s % 9;               // n-tile 0..8
  int t   = xcd + 8 * (s / 9);   // token-tile 0..255

  const int tid = threadIdx.x;
  const int tx  = tid & 15;      // col group (4 cols)
  const int ty  = tid >> 4;      // row group (8 rows), 0..15
  const int m0  = t * BM;
  const int n0  = j * BN;

  float acc[8][4];    // current-panel chain
  float carry[8][4];  // folded previous panels
  #pragma unroll
  for (int i = 0; i < 8; ++i)
    #pragma unroll
    for (int c = 0; c < 4; ++c) { acc[i][c] = 0.f; carry[i][c] = 0.f; }

  // A staging map: thread -> (row = tid>>1, kc = tid&1), 4 float4 along k
  const int arow = tid >> 1;
  const int akc  = tid & 1;
  const float* Ag = A + (size_t)(m0 + arow) * HDIM + akc * 16;

  for (int k0 = 0; k0 < HDIM; k0 += BK) {
    // panel fold at OpenBLAS KC boundaries (384, 768)
    if (k0 == KC || k0 == 2 * KC) {
      #pragma unroll
      for (int i = 0; i < 8; ++i)
        #pragma unroll
        for (int c = 0; c < 4; ++c) {
          carry[i][c] = carry[i][c] + acc[i][c];  // plain fp32 add
          acc[i][c] = 0.f;
        }
    }

    float4 av[4];
    #pragma unroll
    for (int c = 0; c < 4; ++c)
      av[c] = *(const float4*)(Ag + k0 + c * 4);
    float4 bv[2];
    #pragma unroll
    for (int c = 0; c < 2; ++c) {
      int idx = tid + c * 256;
      int kr  = idx >> 4;        // 0..31
      int ch  = idx & 15;        // 0..15
      bv[c] = *(const float4*)&g_Bmat[(size_t)(k0 + kr) * NOUT + n0 + ch * 4];
    }
    __syncthreads();  // protect LDS reuse from previous iteration
    #pragma unroll
    for (int c = 0; c < 4; ++c) {
      int kb = akc * 16 + c * 4;
      As[kb + 0][arow] = av[c].x;
      As[kb + 1][arow] = av[c].y;
      As[kb + 2][arow] = av[c].z;
      As[kb + 3][arow] = av[c].w;
    }
    #pragma unroll
    for (int c = 0; c < 2; ++c) {
      int idx = tid + c * 256;
      int kr  = idx >> 4;
      int ch  = idx & 15;
      *(float4*)&Bs[kr][ch * 4] = bv[c];
    }
    __syncthreads();

    // sequential-k fmaf chains (single accumulator per element, k ascending)
    #pragma unroll 4
    for (int kk = 0; kk < BK; ++kk) {
      float4 a03 = *(const float4*)&As[kk][ty * 8 + 0];
      float4 a47 = *(const float4*)&As[kk][ty * 8 + 4];
      float a[8] = {a03.x, a03.y, a03.z, a03.w, a47.x, a47.y, a47.z, a47.w};
      float b[4];
      b[0] = Bs[kk][tx * 4 + 0];
      b[1] = Bs[kk][tx * 4 + 1];
      b[2] = Bs[kk][tx * 4 + 2];
      b[3] = Bs[kk][tx * 4 + 3];
      #pragma unroll
      for (int i = 0; i < 8; ++i)
        #pragma unroll
        for (int c = 0; c < 4; ++c)
          acc[i][c] = fmaf(a[i], b[c], acc[i][c]);
    }
  }

  // combine final panel: res = (P0+P1) + P2
  float res[8][4];
  #pragma unroll
  for (int i = 0; i < 8; ++i)
    #pragma unroll
    for (int c = 0; c < 4; ++c) res[i][c] = carry[i][c] + acc[i][c];

  // ---- epilogue
  if (j < 8) {
    double w2v[4];
    float  b1v[4];
    #pragma unroll
    for (int c = 0; c < 4; ++c) {
      w2v[c] = (double)W2[n0 + tx * 4 + c];
      b1v[c] = b1[n0 + tx * 4 + c];
    }
    #pragma unroll
    for (int i = 0; i < 8; ++i) {
      double sacc = 0.0;
      #pragma unroll
      for (int c = 0; c < 4; ++c) {
        // h in fp32 exactly as np: (matmul + b1) then relu
        float h = fmaxf(res[i][c] + b1v[c], 0.f);
        sacc = fma((double)h, w2v[c], sacc);
      }
      // reduce across the 16 col-groups (lanes tx = lane&15)
      sacc += __shfl_xor(sacc, 1, 64);
      sacc += __shfl_xor(sacc, 2, 64);
      sacc += __shfl_xor(sacc, 4, 64);
      sacc += __shfl_xor(sacc, 8, 64);
      if (tx == 0) g_partial[(size_t)(m0 + ty * 8 + i) * 8 + j] = sacc;
    }
  } else {
    float brv[4];
    #pragma unroll
    for (int c = 0; c < 4; ++c) brv[c] = b_router[tx * 4 + c];
    #pragma unroll
    for (int i = 0; i < 8; ++i) {
      int row = m0 + ty * 8 + i;
      float o[4];
      #pragma unroll
      for (int c = 0; c < 4; ++c) o[c] = res[i][c] + brv[c];  // fp32 bias add
      *(float4*)&out_logits[(size_t)row * 64 + tx * 4] =
          make_float4(o[0], o[1], o[2], o[3]);
    }
  }
}

// ---------------- kernel 2: per-token postlude, 8 lanes per token ----------------
// Wave = 64 lanes = 8 tokens x 8 lanes. Lane q of a token owns experts
// {q, q+8, ..., q+56} -- exactly the numpy pairwise-8 accumulator lanes, so the
// in-lane ascending-b sum + 3-step shfl_xor tree reproduces
// ((r0+r1)+(r2+r3))+((r4+r5)+(r6+r7)) bit-exactly (fp32 add is commutative, so
// mirrored lane pairs compute identical bit patterns). Max is associative ->
// tree == sequential. expf / true division unchanged -> identical bits.
// Top-8: per-lane strict-> scan (lowest local b == lowest global idx on tie,
// since idx = b*8+q ascends with b), then 3-step shfl argmax with
// tie -> lowest global index: equivalent to the sequential lowest-index scan.
// Confidence in fp64 (tree order; fp64 noise ~1e-16 << ref fp32 noise ~3e-7).
__global__ __launch_bounds__(256) void k_post(const float* __restrict__ b2,
                                              float* __restrict__ d_out) {
  const int lane = threadIdx.x & 63;
  const int wave = threadIdx.x >> 6;       // 0..3
  const int q    = lane & 7;               // lane-within-token
  const int tsub = lane >> 3;              // token-within-wave 0..7
  const int tk   = blockIdx.x * 32 + wave * 8 + tsub;   // < 32768

  // ---- confidence: fp64 tree-sum of the 8 tile partials (coalesced read) ----
  double p = g_partial[(size_t)tk * 8 + q];
  p += __shfl_xor(p, 1, 64);
  p += __shfl_xor(p, 2, 64);
  p += __shfl_xor(p, 4, 64);
  double ca   = (double)b2[0] + p;
  double conf = 1.0 / (1.0 + exp(-ca));
  double dkf  = 1.0 + 7.0 * (1.0 - conf);
  double dkr  = rint(dkf);                 // round half-to-even == jnp.round
  int dk = (int)fmin(fmax(dkr, 1.0), 8.0);

  // ---- logits: lane q loads experts b*8+q (stride-8, L1/L2-resident row) ----
  const float* logits = d_out + OFF_LOG + (size_t)tk * 64;
  float l[8];
  #pragma unroll
  for (int b = 0; b < 8; ++b) l[b] = logits[b * 8 + q];

  // max over 64 (associative -> any order bit-identical)
  float mx = l[0];
  #pragma unroll
  for (int b = 1; b < 8; ++b) mx = fmaxf(mx, l[b]);
  mx = fmaxf(mx, __shfl_xor(mx, 1, 64));
  mx = fmaxf(mx, __shfl_xor(mx, 2, 64));
  mx = fmaxf(mx, __shfl_xor(mx, 4, 64));

  float ex[8];
  #pragma unroll
  for (int b = 0; b < 8; ++b) ex[b] = expf(l[b] - mx);

  // numpy pairwise-8 base case: r[q] = ex[q] + ex[8+q] + ... (b ascending)
  float r = ex[0];
  #pragma unroll
  for (int b = 1; b < 8; ++b) r += ex[b];
  // ((r0+r1)+(r2+r3)) + ((r4+r5)+(r6+r7)) via commutative xor-tree
  r += __shfl_xor(r, 1, 64);
  r += __shfl_xor(r, 2, 64);
  float ssum = r + __shfl_xor(r, 4, 64);

  float v[8];
  #pragma unroll
  for (int b = 0; b < 8; ++b) v[b] = ex[b] / ssum;   // true IEEE division

  // ---- stable top-8 (strict >, ties keep lowest global expert index) ----
  float myw = 0.f, myi = 0.f;      // lane q records slot q's outputs
  unsigned used = 0u;
  #pragma unroll
  for (int slot = 0; slot < 8; ++slot) {
    float best = -1.f;
    int   bi   = 64;               // sentinel, never survives (all v > -1)
    #pragma unroll
    for (int b = 0; b < 8; ++b) {
      bool ok = (((used >> b) & 1u) == 0u) && (v[b] > best);
      best = ok ? v[b] : best;
      bi   = ok ? (b * 8 + q) : bi;
    }
    #pragma unroll
    for (int m = 1; m <= 4; m <<= 1) {
      float ow = __shfl_xor(best, m, 64);
      int   oi = __shfl_xor(bi,   m, 64);
      bool take = (ow > best) || (ow == best && oi < bi);
      best = take ? ow : best;
      bi   = take ? oi : bi;
    }
    if ((bi & 7) == q) used |= (1u << (bi >> 3));   // owning lane retires it
    bool active = slot < dk;
    if (slot == q) {
      myw = active ? best : 0.f;
      myi = active ? (float)bi : 0.f;
    }
  }

  // wave writes 64 consecutive floats: tokens x slots, fully coalesced
  d_out[OFF_SELW + (size_t)tk * 8 + q] = myw;
  d_out[OFF_SELI + (size_t)tk * 8 + q] = myi;
  if (q == 0) d_out[OFF_CONF + tk] = (float)conf;
}

extern "C" void kernel_launch(void* const* d_in, const int* in_sizes, int n_in,
                              void* d_out, int out_size, void* d_ws, size_t ws_size,
                              hipStream_t stream) {
  const float* hidden   = (const float*)d_in[0];
  const float* W_router = (const float*)d_in[1];
  const float* b_router = (const float*)d_in[2];
  const float* W1       = (const float*)d_in[3];
  const float* b1       = (const float*)d_in[4];
  const float* W2       = (const float*)d_in[5];
  const float* b2       = (const float*)d_in[6];
  float* out = (float*)d_out;

  k_build<<<(HDIM * NOUT) / 256, 256, 0, stream>>>(W1, W_router);
  k_gemm<<<(N_TOK / BM) * 9, THREADS, 0, stream>>>(hidden, b1, W2, b_router,
                                                   out + OFF_LOG);
  k_post<<<N_TOK / 256 / 128 * 128 ? (N_TOK / 32) : (N_TOK / 32), 256, 0, stream>>>(b2, out);
}